// Round 16
// baseline (96.630 us; speedup 1.0000x reference)
//
#include <hip/hip_runtime.h>
#include <math.h>

#define NB 512              // blocks; each handles 2 batches
#define NN 512
#define ND 128
#define NT 512

typedef float f4 __attribute__((ext_vector_type(4)));

__device__ __forceinline__ f4 ldnt(const float* p) {
    return __builtin_nontemporal_load(reinterpret_cast<const f4*>(p));
}

#define QSC4   3.75f
#define DQSC4  (1.0f / 3.75f)
#define TSCALE (1.0f / (1440.0f * 1.4142135623730951f))

__global__ __launch_bounds__(NT, 4) void darp_fused(
    const float* __restrict__ node_emb,
    const float* __restrict__ W_last,
    const float* __restrict__ W_first,
    const float* __restrict__ W_graph,
    const float* __restrict__ W_visited,
    const float* __restrict__ W_key,
    const float* __restrict__ W_state,
    const float* __restrict__ b_state,
    const float* __restrict__ current_time,
    const float* __restrict__ used_capacity,
    const float* __restrict__ vehicle_capacity,
    const float* __restrict__ ttm,
    const int* __restrict__ current_node,
    const int* __restrict__ previous_action,
    const int* __restrict__ first_node,
    const int* __restrict__ visited,
    const int* __restrict__ action_mask,
    const int* __restrict__ step_i,
    const int* __restrict__ h3_indices,
    float* __restrict__ out)
{
    const int b0   = blockIdx.x * 2;
    const int b1   = b0 + 1;
    const int t    = threadIdx.x;   // 0..511
    const int wave = t >> 6;        // 0..7
    const int lane = t & 63;
    const int l5   = t & 31;
    const int hb   = lane >> 5;
    const int strm = t >> 5;        // 0..15

    __shared__ unsigned int tileA[(NN / 2) * 32];   // 32 KB int4, batch b0
    __shared__ unsigned int tileB[(NN / 2) * 32];   // 32 KB int4, batch b1
    __shared__ float uni[2048] __attribute__((aligned(16))); // sghf[8*128]+svhf[8*128] -> scratch
    __shared__ unsigned long long smask[8];
    __shared__ float smean0[ND], svis0[ND], smean1[ND], svis1[ND];
    __shared__ float shcur0[ND], shfirst0[ND], shcur1[ND], shfirst1[ND];
    __shared__ float qs[ND];
    __shared__ float qp[ND] __attribute__((aligned(16)));
    __shared__ float sred[8];
    __shared__ float s_scal[4];
    __shared__ float s_qsum;
    __shared__ float s_vc1;

    float* sghf = uni;            // [8][128]
    float* svhf = uni + 1024;     // [8][128]
    float* scratch = uni;         // reuse in stage 4

    const float* nb0 = node_emb + (size_t)b0 * NN * ND;
    const float* nb1 = node_emb + (size_t)b1 * NN * ND;

    // ---- prologue: cur/fn both batches, early h-loads for b0 ---------------
    int cur0 = current_node[b0], fn0 = first_node[b0];
    { int pv = previous_action[b0];
      if (pv == 0 && cur0 != 0) fn0 = cur0;
      if (cur0 == 0) fn0 = 0; }
    int cur1 = current_node[b1], fn1 = first_node[b1];
    { int pv = previous_action[b1];
      if (pv == 0 && cur1 != 0) fn1 = cur1;
      if (cur1 == 0) fn1 = 0; }

    float4 hc4, hf4;
    if (t < 32)       hc4 = *reinterpret_cast<const float4*>(nb0 + (size_t)cur0 * ND + t * 4);
    else if (t < 64)  hf4 = *reinterpret_cast<const float4*>(nb0 + (size_t)fn0  * ND + (t - 32) * 4);

    // visited ballots for b0 + vcount partials; zero b1 accumulators
    {
        const int f = (visited[(size_t)b0 * NN + t] != 0);
        unsigned long long m = __ballot(f);
        if (lane == 0) smask[wave] = m;
        float vc = f ? 1.0f : 0.0f;
#pragma unroll
        for (int off = 32; off >= 1; off >>= 1) vc += __shfl_xor(vc, off);
        if (lane == 0) sred[wave] = vc;
    }
    if (t < 128) { smean1[t] = 0.f; svis1[t] = 0.f; }
    if (t == 128) s_vc1 = 0.f;
    if (t < 32)       *reinterpret_cast<float4*>(&shcur0[t * 4]) = hc4;
    else if (t < 64)  *reinterpret_cast<float4*>(&shfirst0[(t - 32) * 4]) = hf4;
    __syncthreads();

    // ---- Stage 2: all 8 waves stream b0 -> tileA + colsum partials --------
    {
        const int r0 = strm * 32;
        const float* p = nb0 + (size_t)r0 * ND + l5 * 4;
        const unsigned int mybits =
            (unsigned int)(smask[strm >> 1] >> ((strm & 1) * 32));
        unsigned int* tw = tileA + (r0 >> 1) * 32;
        const int pbase = strm * 16;

        float4 g = make_float4(0.f, 0.f, 0.f, 0.f);
        float4 v = make_float4(0.f, 0.f, 0.f, 0.f);
        unsigned int held = 0;

        f4 xa[8], xb[8];
#pragma unroll
        for (int u = 0; u < 8; ++u) xa[u] = ldnt(p + (size_t)u * ND);
#pragma unroll
        for (int u = 0; u < 8; ++u) xb[u] = ldnt(p + (size_t)(8 + u) * ND);

#define PROC8(BUF, BASE)                                                       \
        {                                                                      \
            _Pragma("unroll")                                                  \
            for (int u = 0; u < 8; ++u) {                                      \
                const f4 X = BUF[u];                                           \
                const int k = (BASE) + u;                                      \
                const float vf = ((mybits >> k) & 1u) ? 1.0f : 0.0f;           \
                g.x += X.x; g.y += X.y; g.z += X.z; g.w += X.w;                \
                v.x = fmaf(vf, X.x, v.x); v.y = fmaf(vf, X.y, v.y);            \
                v.z = fmaf(vf, X.z, v.z); v.w = fmaf(vf, X.w, v.w);            \
                const float c0 = fminf(fmaxf(fmaf(X.x, QSC4, 8.49f), 0.f), 15.49f); \
                const float c1 = fminf(fmaxf(fmaf(X.y, QSC4, 8.49f), 0.f), 15.49f); \
                const float c2 = fminf(fmaxf(fmaf(X.z, QSC4, 8.49f), 0.f), 15.49f); \
                const float c3 = fminf(fmaxf(fmaf(X.w, QSC4, 8.49f), 0.f), 15.49f); \
                const unsigned int h16 = (unsigned int)(int)c0                 \
                    | ((unsigned int)(int)c1 << 4)                             \
                    | ((unsigned int)(int)c2 << 8)                             \
                    | ((unsigned int)(int)c3 << 12);                           \
                if (k & 1) {                                                   \
                    const int pl = k >> 1;                                     \
                    tw[pl * 32 + (l5 ^ ((pbase + pl) & 31))] = held | (h16 << 16); \
                } else {                                                       \
                    held = h16;                                                \
                }                                                              \
            }                                                                  \
        }

        PROC8(xa, 0)
#pragma unroll
        for (int u = 0; u < 8; ++u) xa[u] = ldnt(p + (size_t)(16 + u) * ND);
        PROC8(xb, 8)
#pragma unroll
        for (int u = 0; u < 8; ++u) xb[u] = ldnt(p + (size_t)(24 + u) * ND);
        PROC8(xa, 16)
        PROC8(xb, 24)
#undef PROC8

        g.x += __shfl_xor(g.x, 32); g.y += __shfl_xor(g.y, 32);
        g.z += __shfl_xor(g.z, 32); g.w += __shfl_xor(g.w, 32);
        v.x += __shfl_xor(v.x, 32); v.y += __shfl_xor(v.y, 32);
        v.z += __shfl_xor(v.z, 32); v.w += __shfl_xor(v.w, 32);
        if (lane < 32) {
            *reinterpret_cast<float4*>(&sghf[wave * 128 + l5 * 4]) = g;
            *reinterpret_cast<float4*>(&svhf[wave * 128 + l5 * 4]) = v;
        }
    }
    __syncthreads();

    // ---- Stage 3: waves 0-6 stream b1; wave 7 runs b0's full tail ---------
    if (wave == 7) {
        // colsum finalize for b0
        for (int c = lane; c < 128; c += 64) {
            float G = 0.f, V = 0.f;
#pragma unroll
            for (int j = 0; j < 8; ++j) { G += sghf[j * 128 + c]; V += svhf[j * 128 + c]; }
            smean0[c] = G * (1.0f / (float)NN);
            svis0[c]  = V;
        }
        float vcnt = sred[0] + sred[1] + sred[2] + sred[3]
                   + sred[4] + sred[5] + sred[6] + sred[7];
        const float inv_vc = 1.0f / fmaxf(vcnt, 1.0f);
        const float cap = vehicle_capacity[b0] - used_capacity[b0];
        const float ctm = current_time[b0] * (1.0f / 1440.0f);
        const float sf  = (float)step_i[b0] * (1.0f / (2.0f * (float)NN));

        // B1: q[e]
        for (int e = lane; e < 128; e += 64) {
            float a0 = 0.f, a1 = 0.f, a2 = 0.f, a3 = 0.f;
#pragma unroll 4
            for (int d = 0; d < 128; ++d) {
                a0 = fmaf(shcur0[d],   W_last[d * ND + e],    a0);
                a1 = fmaf(shfirst0[d], W_first[d * ND + e],   a1);
                a2 = fmaf(smean0[d],   W_graph[d * ND + e],   a2);
                a3 = fmaf(svis0[d],    W_visited[d * ND + e], a3);
            }
            qs[e] = a0 + a1 + a2 + inv_vc * a3 + b_state[e]
                  + cap * W_state[e] + ctm * W_state[ND + e] + sf * W_state[2 * ND + e];
        }
        // B2: q'[d] + qsum
        float qsum = 0.f;
        for (int d = lane; d < 128; d += 64) {
            float s = 0.f;
#pragma unroll 4
            for (int e = 0; e < 128; ++e) s = fmaf(W_key[d * ND + e], qs[e], s);
            const float qv = s * (0.08838834764831845f * DQSC4);
            qp[d] = qv; qsum += qv;
        }
#pragma unroll
        for (int off = 32; off >= 1; off >>= 1) qsum += __shfl_xor(qsum, off);

        // C+D: 8 rows/lane
        const int    ch3  = h3_indices[(size_t)b0 * NN + cur0];
        const float* trow = ttm + (size_t)ch3 * NN;
        float sr[8];
#pragma unroll
        for (int i = 0; i < 8; ++i) {
            const int r = lane + 64 * i;
            const int pair = r >> 1, hi = (r & 1) * 16, sw = pair & 31;
            const unsigned int* tr = tileA + pair * 32;
            float s1 = 0.f;
#pragma unroll 8
            for (int c = 0; c < 32; ++c) {
                const unsigned int wd = tr[c ^ sw];
                const unsigned int h = (wd >> hi) & 0xffffu;
                const float4 q4 = *reinterpret_cast<const float4*>(&qp[c * 4]);
                s1 = fmaf((float)(h & 15u),        q4.x, s1);
                s1 = fmaf((float)((h >> 4) & 15u), q4.y, s1);
                s1 = fmaf((float)((h >> 8) & 15u), q4.z, s1);
                s1 = fmaf((float)(h >> 12),        q4.w, s1);
            }
            s1 -= 8.0f * qsum;
            const int h1 = h3_indices[(size_t)b0 * NN + r];
            s1 -= trow[h1] * TSCALE;
            s1 = 10.0f * tanhf(s1 * 0.1f);
            if (!action_mask[(size_t)b0 * NN + r]) s1 = -1e8f;
            sr[i] = s1;
        }
        float m = sr[0];
#pragma unroll
        for (int i = 1; i < 8; ++i) m = fmaxf(m, sr[i]);
#pragma unroll
        for (int off = 32; off >= 1; off >>= 1) m = fmaxf(m, __shfl_xor(m, off));
        float es = 0.f;
#pragma unroll
        for (int i = 0; i < 8; ++i) es += expf(sr[i] - m);
#pragma unroll
        for (int off = 32; off >= 1; off >>= 1) es += __shfl_xor(es, off);
        const float lse = m + logf(es);
#pragma unroll
        for (int i = 0; i < 8; ++i)
            out[(size_t)b0 * NN + lane + 64 * i] = sr[i] - lse;
    } else {
        // waves 0-6: stream b1 (pair-contiguous NT), colsums via LDS atomics
        if (wave == 1) {
            if (lane < 32)
                *reinterpret_cast<float4*>(&shcur1[lane * 4]) =
                    *reinterpret_cast<const float4*>(nb1 + (size_t)cur1 * ND + lane * 4);
            else
                *reinterpret_cast<float4*>(&shfirst1[(lane - 32) * 4]) =
                    *reinterpret_cast<const float4*>(nb1 + (size_t)fn1 * ND + (lane - 32) * 4);
        }
        const int* vis1 = visited + (size_t)b1 * NN;
        float4 g = make_float4(0.f, 0.f, 0.f, 0.f);
        float4 v = make_float4(0.f, 0.f, 0.f, 0.f);
        float vc = 0.f;

        int p = wave;                       // 0..6
        f4 cx = ldnt(nb1 + (size_t)p * 2 * ND + lane * 4);
        while (p < 256) {
            const int pn = p + 7;
            f4 nx = cx;
            if (pn < 256) nx = ldnt(nb1 + (size_t)pn * 2 * ND + lane * 4);
            const int row = 2 * p + hb;
            const float vf = vis1[row] ? 1.0f : 0.0f;
            g.x += cx.x; g.y += cx.y; g.z += cx.z; g.w += cx.w;
            v.x = fmaf(vf, cx.x, v.x); v.y = fmaf(vf, cx.y, v.y);
            v.z = fmaf(vf, cx.z, v.z); v.w = fmaf(vf, cx.w, v.w);
            if (l5 == 0) vc += vf;
            const float c0 = fminf(fmaxf(fmaf(cx.x, QSC4, 8.49f), 0.f), 15.49f);
            const float c1 = fminf(fmaxf(fmaf(cx.y, QSC4, 8.49f), 0.f), 15.49f);
            const float c2 = fminf(fmaxf(fmaf(cx.z, QSC4, 8.49f), 0.f), 15.49f);
            const float c3 = fminf(fmaxf(fmaf(cx.w, QSC4, 8.49f), 0.f), 15.49f);
            unsigned int h16 = (unsigned int)(int)c0
                | ((unsigned int)(int)c1 << 4)
                | ((unsigned int)(int)c2 << 8)
                | ((unsigned int)(int)c3 << 12);
            const unsigned int oth = __shfl_down(h16, 32);
            if (lane < 32) tileB[p * 32 + (l5 ^ (p & 31))] = h16 | (oth << 16);
            cx = nx; p = pn;
        }
        g.x += __shfl_xor(g.x, 32); g.y += __shfl_xor(g.y, 32);
        g.z += __shfl_xor(g.z, 32); g.w += __shfl_xor(g.w, 32);
        v.x += __shfl_xor(v.x, 32); v.y += __shfl_xor(v.y, 32);
        v.z += __shfl_xor(v.z, 32); v.w += __shfl_xor(v.w, 32);
        vc  += __shfl_xor(vc, 32);
        if (lane < 32) {
            atomicAdd(&smean1[l5 * 4 + 0], g.x); atomicAdd(&smean1[l5 * 4 + 1], g.y);
            atomicAdd(&smean1[l5 * 4 + 2], g.z); atomicAdd(&smean1[l5 * 4 + 3], g.w);
            atomicAdd(&svis1[l5 * 4 + 0], v.x);  atomicAdd(&svis1[l5 * 4 + 1], v.y);
            atomicAdd(&svis1[l5 * 4 + 2], v.z);  atomicAdd(&svis1[l5 * 4 + 3], v.w);
        }
        if (lane == 0) atomicAdd(&s_vc1, vc);
    }
    __syncthreads();

    // ---- Stage 4: full block tail for b1 ----------------------------------
    if (t == 0) {
        s_scal[0] = 1.0f / fmaxf(s_vc1, 1.0f);
        s_scal[1] = vehicle_capacity[b1] - used_capacity[b1];
        s_scal[2] = current_time[b1] * (1.0f / 1440.0f);
        s_scal[3] = (float)step_i[b1] * (1.0f / (2.0f * (float)NN));
    }
    __syncthreads();

    {
        const int e  = t & 127;
        const int g2 = t >> 7;
        const int d0 = g2 * 32;
        float a0 = 0.f, a1 = 0.f, a2 = 0.f, a3 = 0.f;
#pragma unroll 8
        for (int dd = 0; dd < 32; ++dd) {
            int d = d0 + dd;
            a0 = fmaf(shcur1[d],   W_last[d * ND + e],    a0);
            a1 = fmaf(shfirst1[d], W_first[d * ND + e],   a1);
            a2 = fmaf(smean1[d],   W_graph[d * ND + e],   a2);
            a3 = fmaf(svis1[d],    W_visited[d * ND + e], a3);
        }
        float pacc = a0 + a1 + (1.0f / (float)NN) * a2 + s_scal[0] * a3;
        if (g2 == 0) {
            pacc += b_state[e]
                  + s_scal[1] * W_state[e]
                  + s_scal[2] * W_state[ND + e]
                  + s_scal[3] * W_state[2 * ND + e];
        }
        scratch[g2 * 128 + e] = pacc;
    }
    __syncthreads();

    if (t < ND) qs[t] = scratch[t] + scratch[128 + t]
                      + scratch[256 + t] + scratch[384 + t];
    __syncthreads();

    {
        float4 qv = *reinterpret_cast<const float4*>(&qs[l5 * 4]);
#pragma unroll
        for (int it = 0; it < 8; ++it) {
            int d = it * 16 + strm;
            float4 wk = *reinterpret_cast<const float4*>(W_key + (size_t)d * ND + l5 * 4);
            float s = wk.x * qv.x + wk.y * qv.y + wk.z * qv.z + wk.w * qv.w;
            s += __shfl_xor(s, 16); s += __shfl_xor(s, 8);
            s += __shfl_xor(s, 4);  s += __shfl_xor(s, 2); s += __shfl_xor(s, 1);
            if (l5 == 0) qp[d] = s * (0.08838834764831845f * DQSC4);
        }
    }
    __syncthreads();

    if (t < 64) {
        float s = qp[t] + qp[t + 64];
#pragma unroll
        for (int off = 32; off >= 1; off >>= 1) s += __shfl_xor(s, off);
        if (t == 0) s_qsum = s;
    }
    __syncthreads();

    {
        const int pair = t >> 1;
        const int hi   = (t & 1) * 16;
        const int sw   = pair & 31;
        const unsigned int* tr = tileB + pair * 32;
        float s1 = 0.f;
#pragma unroll 8
        for (int c = 0; c < 32; ++c) {
            const unsigned int wd = tr[c ^ sw];
            const unsigned int h = (wd >> hi) & 0xffffu;
            const float4 q4 = *reinterpret_cast<const float4*>(&qp[c * 4]);
            s1 = fmaf((float)(h & 15u),        q4.x, s1);
            s1 = fmaf((float)((h >> 4) & 15u), q4.y, s1);
            s1 = fmaf((float)((h >> 8) & 15u), q4.z, s1);
            s1 = fmaf((float)(h >> 12),        q4.w, s1);
        }
        s1 -= 8.0f * s_qsum;

        const int    ch3  = h3_indices[(size_t)b1 * NN + cur1];
        const float* trow = ttm + (size_t)ch3 * NN;
        const int h1 = h3_indices[(size_t)b1 * NN + t];
        s1 -= trow[h1] * TSCALE;
        s1 = 10.0f * tanhf(s1 * 0.1f);
        if (!action_mask[(size_t)b1 * NN + t]) s1 = -1e8f;

        float m = s1;
#pragma unroll
        for (int off = 32; off >= 1; off >>= 1) m = fmaxf(m, __shfl_xor(m, off));
        if (lane == 0) sred[wave] = m;
        __syncthreads();
        float bm = fmaxf(fmaxf(fmaxf(sred[0], sred[1]), fmaxf(sred[2], sred[3])),
                         fmaxf(fmaxf(sred[4], sred[5]), fmaxf(sred[6], sred[7])));

        float es = expf(s1 - bm);
#pragma unroll
        for (int off = 32; off >= 1; off >>= 1) es += __shfl_xor(es, off);
        if (lane == 0) sred[wave] = es;   // reuse after all read bm
        __syncthreads();
        float lse = bm + logf(sred[0] + sred[1] + sred[2] + sred[3]
                            + sred[4] + sred[5] + sred[6] + sred[7]);

        out[(size_t)b1 * NN + t] = s1 - lse;
    }
}

extern "C" void kernel_launch(void* const* d_in, const int* in_sizes, int n_in,
                              void* d_out, int out_size, void* d_ws, size_t ws_size,
                              hipStream_t stream) {
    (void)in_sizes; (void)n_in; (void)d_ws; (void)ws_size; (void)out_size;
    darp_fused<<<dim3(NB), dim3(NT), 0, stream>>>(
        (const float*)d_in[0],   // node_emb
        (const float*)d_in[1],   // W_last
        (const float*)d_in[2],   // W_first
        (const float*)d_in[3],   // W_graph
        (const float*)d_in[4],   // W_visited
        (const float*)d_in[5],   // W_key
        (const float*)d_in[6],   // W_state
        (const float*)d_in[7],   // b_state
        (const float*)d_in[8],   // current_time
        (const float*)d_in[9],   // used_capacity
        (const float*)d_in[10],  // vehicle_capacity
        (const float*)d_in[11],  // travel_time_matrix
        (const int*)d_in[12],    // current_node
        (const int*)d_in[13],    // previous_action
        (const int*)d_in[14],    // first_node
        (const int*)d_in[15],    // visited (bool as int32)
        (const int*)d_in[16],    // action_mask (bool as int32)
        (const int*)d_in[17],    // i
        (const int*)d_in[18],    // h3_indices
        (float*)d_out);
}